// Round 5
// baseline (131.933 us; speedup 1.0000x reference)
//
#include <hip/hip_runtime.h>

#define NN 1024
#define MM 1024
#define DD 256

typedef float floatx2 __attribute__((ext_vector_type(2)));

__device__ __forceinline__ float rcp_fast(float x) { return __builtin_amdgcn_rcpf(x); }

// ---------------- K1: fused dual GEMM + exp epilogue (unchanged) ----------------
// blocks 0..127:   q = f_r @ W_w^T + W_b    -> Eq[n][d]  = exp(2q)   (clamped +-5)
// blocks 128..255: k = f_rp @ Wp_w^T + Wp_b -> EkT[d][m] = exp(2k)   (LDS-transposed)
// Block 0 also zeroes d_out for K3's atomicAdd.
__global__ __launch_bounds__(256) void gemm_exp_kernel(
    const float* __restrict__ f_r,  const float* __restrict__ W_w,  const float* __restrict__ W_b,
    const float* __restrict__ f_rp, const float* __restrict__ Wp_w, const float* __restrict__ Wp_b,
    float* __restrict__ Eq, float* __restrict__ EkT, float* __restrict__ out0)
{
    __shared__ float As[32][36];   // [k][r]
    __shared__ float Bs[32][68];   // [k][d]
    __shared__ float T[64][36];    // k-path transpose buffer [d_local][r_local]

    const int b = blockIdx.x;
    const int t = threadIdx.x;
    if (b == 0) out0[t] = 0.f;     // zero d_out (256 floats)

    const int mat  = b >> 7;
    const int tile = b & 127;
    const int rt = tile & 31, dt = tile >> 5;
    const float* __restrict__ A    = mat ? f_rp : f_r;
    const float* __restrict__ B    = mat ? Wp_w : W_w;
    const float* __restrict__ bias = mat ? Wp_b : W_b;

    const int tx = t & 15, ty = t >> 4;          // tx -> 4 d-cols, ty -> 2 r-rows
    const int r0 = rt * 32, d0 = dt * 64;
    const int ar = t >> 3, ak = (t & 7) * 4;     // A stage: 32 rows x 32 k
    const int br = t >> 2, bk = (t & 3) * 8;     // B stage: 64 rows x 32 k

    float acc[2][4];
    #pragma unroll
    for (int i = 0; i < 2; ++i)
        #pragma unroll
        for (int j = 0; j < 4; ++j) acc[i][j] = 0.f;

    for (int kk = 0; kk < DD; kk += 32) {
        float4 av  = *(const float4*)(A + (size_t)(r0 + ar) * DD + kk + ak);
        float4 bv0 = *(const float4*)(B + (size_t)(d0 + br) * DD + kk + bk);
        float4 bv1 = *(const float4*)(B + (size_t)(d0 + br) * DD + kk + bk + 4);
        __syncthreads();
        As[ak + 0][ar] = av.x; As[ak + 1][ar] = av.y; As[ak + 2][ar] = av.z; As[ak + 3][ar] = av.w;
        Bs[bk + 0][br] = bv0.x; Bs[bk + 1][br] = bv0.y; Bs[bk + 2][br] = bv0.z; Bs[bk + 3][br] = bv0.w;
        Bs[bk + 4][br] = bv1.x; Bs[bk + 5][br] = bv1.y; Bs[bk + 6][br] = bv1.z; Bs[bk + 7][br] = bv1.w;
        __syncthreads();
        #pragma unroll
        for (int k = 0; k < 32; ++k) {
            float2 a2 = *(const float2*)&As[k][ty * 2];
            float4 b4 = *(const float4*)&Bs[k][tx * 4];
            float aa[2] = {a2.x, a2.y};
            float bb[4] = {b4.x, b4.y, b4.z, b4.w};
            #pragma unroll
            for (int i = 0; i < 2; ++i)
                #pragma unroll
                for (int j = 0; j < 4; ++j)
                    acc[i][j] = fmaf(aa[i], bb[j], acc[i][j]);
        }
    }

    float bj[4];
    #pragma unroll
    for (int j = 0; j < 4; ++j) bj[j] = bias[d0 + tx * 4 + j];

    float e[2][4];
    #pragma unroll
    for (int i = 0; i < 2; ++i)
        #pragma unroll
        for (int j = 0; j < 4; ++j) {
            float v = acc[i][j] + bj[j];
            // +-5: tanh(5)=0.9999092 (error 9e-5, negligible after w-weighting);
            // also bounds the no-max exp in K2a: |s~| <= 2*sum|w| <= 32 -> e^32 << fp32 max.
            v = fminf(fmaxf(v, -5.f), 5.f);
            e[i][j] = __expf(2.f * v);
        }

    if (mat == 0) {
        #pragma unroll
        for (int i = 0; i < 2; ++i)
            *(float4*)&Eq[(size_t)(r0 + ty * 2 + i) * DD + d0 + tx * 4] =
                make_float4(e[i][0], e[i][1], e[i][2], e[i][3]);
    } else {
        __syncthreads();
        #pragma unroll
        for (int i = 0; i < 2; ++i)
            #pragma unroll
            for (int j = 0; j < 4; ++j) T[tx * 4 + j][ty * 2 + i] = e[i][j];
        __syncthreads();
        const int dl = t >> 3, rl = (t & 7) * 4;
        #pragma unroll
        for (int h = 0; h < 2; ++h) {
            int dloc = dl + 32 * h;
            float4 tv = *(const float4*)&T[dloc][rl];
            *(float4*)&EkT[(size_t)(d0 + dloc) * MM + r0 + rl] = tv;
        }
    }
}

// ---------------- K2a: scores, barrier-minimal (GEOMETRY FIXED) ----------------
// 512 blocks x 512 thr; block = (n-quad = bid>>1, m-HALF = bid&1, m0 = bm*512).
// Thread: dh = t>>8 (d-half), tm = t&255 (m-pair within the 512-wide half ->
// m0 + 2*tm, 2*tm+1). 256 tm-threads x 2 m = 512 m = the half: decode now
// matches the per-thread mapping (round-4 bug: block claimed a 256-quarter
// while threads spanned 512 -> overlap + OOB).
// Each thread accumulates s~ partials for 4n x 2m over its 128-d half ENTIRELY
// in registers (one 2-way LDS combine, one barrier). NO-MAX exp (|s~|<=32),
// e -> global E, per-(n, half) denominators -> Sp2 (deterministic, no atomics).
__global__ __launch_bounds__(512, 8) void score_kernel(
    const float* __restrict__ Eq, const float* __restrict__ EkT,
    const float* __restrict__ w_w,
    float* __restrict__ E, float* __restrict__ Sp2)
{
    __shared__ float2 part[2][4][256];   // 16 KB partial s~ per d-half
    __shared__ float wred[4][4];

    const int t  = threadIdx.x;
    const int dh = t >> 8;               // d-half (wave-uniform)
    const int tm = t & 255;              // m-pair index within the half
    const int ng = blockIdx.x >> 1;
    const int bm = blockIdx.x & 1;
    const int n0 = ng * 4;
    const int m0 = bm * 512;

    // wave-uniform scalar bases
    const int dbase = __builtin_amdgcn_readfirstlane(dh * 128);
    const float* __restrict__ eqb = Eq + (size_t)n0 * DD + dbase;
    const float* __restrict__ wwb = w_w + dbase;
    const float* __restrict__ ekb = EkT + (size_t)dbase * MM + m0 + 2 * tm;

    const floatx2 one2 = {1.f, 1.f};
    floatx2 acc[4] = {{0.f,0.f},{0.f,0.f},{0.f,0.f},{0.f,0.f}};

    // software-prefetch rotation over 32 d-groups of 4
    float2 c0 = *(const float2*)(ekb + 0 * MM);
    float2 c1 = *(const float2*)(ekb + 1 * MM);
    float2 c2 = *(const float2*)(ekb + 2 * MM);
    float2 c3 = *(const float2*)(ekb + 3 * MM);

    for (int gi = 0; gi < 32; ++gi) {
        float2 p0 = c0, p1 = c1, p2 = c2, p3 = c3;
        if (gi < 31) {
            const float* nb = ekb + (size_t)(gi * 4 + 4) * MM;
            p0 = *(const float2*)(nb + 0 * MM);
            p1 = *(const float2*)(nb + 1 * MM);
            p2 = *(const float2*)(nb + 2 * MM);
            p3 = *(const float2*)(nb + 3 * MM);
        }
        const int db = gi * 4;
        float4 w4 = *(const float4*)(wwb + db);            // scalar (uniform)
        floatx2 kv0 = {c0.x, c0.y}, kv1 = {c1.x, c1.y};
        floatx2 kv2 = {c2.x, c2.y}, kv3 = {c3.x, c3.y};
        #pragma unroll
        for (int n = 0; n < 4; ++n) {
            float4 q4 = *(const float4*)(eqb + n * DD + db);   // scalar (uniform)
            // sum_{i=0..3} w_i/x_i  via 4-way rcp combining, x_i = q_i*k_i+1
            floatx2 x0 = q4.x * kv0 + one2;
            floatx2 x1 = q4.y * kv1 + one2;
            floatx2 x2 = q4.z * kv2 + one2;
            floatx2 x3 = q4.w * kv3 + one2;
            floatx2 p01 = x0 * x1;
            floatx2 p23 = x2 * x3;
            floatx2 n01 = w4.x * x1 + w4.y * x0;
            floatx2 n23 = w4.z * x3 + w4.w * x2;
            floatx2 nc  = n01 * p23 + n23 * p01;
            floatx2 pt  = p01 * p23;
            floatx2 r;  r.x = rcp_fast(pt.x);  r.y = rcp_fast(pt.y);
            acc[n] += nc * r;
        }
        c0 = p0; c1 = p1; c2 = p2; c3 = p3;
    }

    #pragma unroll
    for (int n = 0; n < 4; ++n)
        part[dh][n][tm] = make_float2(acc[n].x, acc[n].y);
    __syncthreads();

    // epilogue on d-half-0 threads: combine halves, exp, write e, wave-reduce denom
    const int lane = t & 63;
    if (t < 256) {
        #pragma unroll
        for (int n = 0; n < 4; ++n) {
            float2 a = part[0][n][t];
            float2 b = part[1][n][t];
            float ex = __expf(-2.f * (a.x + b.x));   // bounded: |s~| <= 32
            float ey = __expf(-2.f * (a.y + b.y));
            *(float2*)&E[(size_t)(n0 + n) * MM + m0 + 2 * t] = make_float2(ex, ey);
            float sm = ex + ey;
            #pragma unroll
            for (int off = 32; off > 0; off >>= 1) sm += __shfl_xor(sm, off);
            if (lane == 0) wred[n][t >> 6] = sm;
        }
    }
    __syncthreads();
    if (t < 4)
        Sp2[(size_t)(n0 + t) * 2 + bm] =
            wred[t][0] + wred[t][1] + wred[t][2] + wred[t][3];
}

// ---------------- K2b: ctx = e @ frp + normalize + stage-2 score ----------------
// 256 blocks x 1024 thr; block = n-quad over full m. cc = t&63 -> 4 d-cols,
// rr = wave id -> 64-m range; e loads are wave-uniform -> scalar path; frp
// float4 vector loads; LDS range-combine; fused normalize (S from Sp2) and
// stage-2 score[n] = ctx[n] . wp_w.
__global__ __launch_bounds__(1024, 8) void ctx_kernel(
    const float* __restrict__ E, const float* __restrict__ frp,
    const float* __restrict__ Sp2, const float* __restrict__ wp_w,
    float* __restrict__ ctx, float* __restrict__ score)
{
    __shared__ float4 ctxred[16][4][64];  // 64 KB range-combine slabs
    __shared__ float redsc[16];

    const int t = threadIdx.x;
    const int n0 = blockIdx.x * 4;
    const int cc = t & 63;
    const int lane = t & 63;
    const int rr = __builtin_amdgcn_readfirstlane(t >> 6);   // wave id = m-range
    const int m0 = rr * 64;

    floatx2 axl[4] = {{0.f,0.f},{0.f,0.f},{0.f,0.f},{0.f,0.f}};
    floatx2 axh[4] = {{0.f,0.f},{0.f,0.f},{0.f,0.f},{0.f,0.f}};
    const float* fb = frp + (size_t)m0 * DD + 4 * cc;
    const float* eb = E + (size_t)n0 * MM + m0;

    for (int m4 = 0; m4 < 16; ++m4) {
        float alv[4][4];
        #pragma unroll
        for (int n = 0; n < 4; ++n) {
            float4 a4 = *(const float4*)(eb + (size_t)n * MM + m4 * 4);  // uniform
            alv[n][0] = a4.x; alv[n][1] = a4.y; alv[n][2] = a4.z; alv[n][3] = a4.w;
        }
        #pragma unroll
        for (int mm = 0; mm < 4; ++mm) {
            float4 f = *(const float4*)(fb + (size_t)(m4 * 4 + mm) * DD);
            floatx2 fl = {f.x, f.y}, fh = {f.z, f.w};
            #pragma unroll
            for (int n = 0; n < 4; ++n) {
                axl[n] += alv[n][mm] * fl;
                axh[n] += alv[n][mm] * fh;
            }
        }
    }
    #pragma unroll
    for (int n = 0; n < 4; ++n)
        ctxred[rr][n][cc] = make_float4(axl[n].x, axl[n].y, axh[n].x, axh[n].y);
    __syncthreads();

    // final range-reduce + normalize: thread t -> (nn = t>>8, d = t&255)
    const int nn = __builtin_amdgcn_readfirstlane(t >> 8);
    const int d = t & 255;
    float s = 0.f;
    #pragma unroll
    for (int r = 0; r < 16; ++r)
        s += ((const float*)&ctxred[r][nn][d >> 2])[d & 3];
    const int row = n0 + nn;
    const float S = Sp2[(size_t)row * 2 + 0] + Sp2[(size_t)row * 2 + 1];
    float sn = s * rcp_fast(S);
    ctx[(size_t)row * DD + d] = sn;

    float p = sn * wp_w[d];
    #pragma unroll
    for (int off = 32; off > 0; off >>= 1) p += __shfl_xor(p, off);
    if (lane == 0) redsc[t >> 6] = p;
    __syncthreads();
    if (t < 4)
        score[n0 + t] = redsc[4 * t] + redsc[4 * t + 1] + redsc[4 * t + 2] + redsc[4 * t + 3];
}

// ---------------- K3: softmax over N (redundant per block) + pooled sum ----------------
// 256 blocks x 256 thr; block b handles n-rows 4b..4b+3.
__global__ __launch_bounds__(256) void pool_kernel(
    const float* __restrict__ ctx, const float* __restrict__ score,
    float* __restrict__ out)
{
    __shared__ float red[8];
    const int t = threadIdx.x, lane = t & 63, wid = t >> 6;
    const int n0 = blockIdx.x * 4;

    float s0 = score[t], s1 = score[t + 256], s2 = score[t + 512], s3 = score[t + 768];
    float mx = fmaxf(fmaxf(s0, s1), fmaxf(s2, s3));
    #pragma unroll
    for (int off = 32; off > 0; off >>= 1) mx = fmaxf(mx, __shfl_xor(mx, off));
    if (lane == 0) red[wid] = mx;
    __syncthreads();
    mx = fmaxf(fmaxf(red[0], red[1]), fmaxf(red[2], red[3]));

    float se = __expf(s0 - mx) + __expf(s1 - mx) + __expf(s2 - mx) + __expf(s3 - mx);
    #pragma unroll
    for (int off = 32; off > 0; off >>= 1) se += __shfl_xor(se, off);
    if (lane == 0) red[4 + wid] = se;
    __syncthreads();
    se = red[4] + red[5] + red[6] + red[7];
    float invS = rcp_fast(se);

    float r = 0.f;
    #pragma unroll
    for (int i = 0; i < 4; ++i) {
        float ap = __expf(score[n0 + i] - mx) * invS;   // wave-uniform broadcast load
        r = fmaf(ap, ctx[(size_t)(n0 + i) * DD + t], r);
    }
    atomicAdd(out + t, r);
}

extern "C" void kernel_launch(void* const* d_in, const int* in_sizes, int n_in,
                              void* d_out, int out_size, void* d_ws, size_t ws_size,
                              hipStream_t stream) {
    const float* f_r  = (const float*)d_in[0];
    const float* f_rp = (const float*)d_in[1];
    const float* W_w  = (const float*)d_in[2];
    const float* W_b  = (const float*)d_in[3];
    const float* Wp_w = (const float*)d_in[4];
    const float* Wp_b = (const float*)d_in[5];
    const float* w_w  = (const float*)d_in[6];
    // d_in[7] = w_b  : cancels in softmax over m
    const float* wp_w = (const float*)d_in[8];
    // d_in[9] = wp_b : cancels in softmax over n
    float* out = (float*)d_out;

    float* ws    = (float*)d_ws;
    float* Eq    = ws;                  // 262144 floats (1 MB)
    float* EkT   = ws + 262144;         // 262144 (1 MB)
    float* E     = ws + 524288;         // 1048576 (4 MB) unnormalized exp(scores)
    float* ctx   = ws + 1572864;        // 262144 (1 MB) normalized context
    float* Sp2   = ws + 1835008;        // 2048   per-(n, m-half) denominators
    float* score = ws + 1837056;        // 1024

    gemm_exp_kernel<<<256, 256, 0, stream>>>(f_r, W_w, W_b, f_rp, Wp_w, Wp_b, Eq, EkT, out);
    score_kernel<<<512, 512, 0, stream>>>(Eq, EkT, w_w, E, Sp2);
    ctx_kernel<<<256, 1024, 0, stream>>>(E, f_rp, Sp2, wp_w, ctx, score);
    pool_kernel<<<256, 256, 0, stream>>>(ctx, score, out);
}